// Round 7
// baseline (268.091 us; speedup 1.0000x reference)
//
#include <hip/hip_runtime.h>
#include <hip/hip_bf16.h>

#define NA   312      // attributes
#define LAT  64       // latent per attribute (K)
#define HID  128      // hidden per attribute (N)
#define NB   8192     // batch
#define MB   256      // rows per tile (4 waves x 64 rows)
#define NBT  (NB / MB)    // 32 batch tiles
#define NT   (NA * NBT)   // 9984 tiles
#define GRID 512          // persistent blocks, 2 per CU

typedef __attribute__((ext_vector_type(8))) short bf16x8;
typedef __attribute__((ext_vector_type(4))) float f32x4;

// fp32 -> bf16 RNE scalar (prep kernel only)
__device__ inline short f2bf(float f) {
    unsigned u = __builtin_bit_cast(unsigned, f);
    u += 0x7FFFu + ((u >> 16) & 1u);
    return (short)(u >> 16);
}

// 8x fp32 -> bf16x8; __float22bfloat162_rn lowers to v_cvt_pk_bf16_f32.
__device__ inline bf16x8 pack8(float4 v0, float4 v1) {
    __hip_bfloat162 c[4] = {
        __float22bfloat162_rn(float2{v0.x, v0.y}),
        __float22bfloat162_rn(float2{v0.z, v0.w}),
        __float22bfloat162_rn(float2{v1.x, v1.y}),
        __float22bfloat162_rn(float2{v1.z, v1.w})};
    bf16x8 f;
    __builtin_memcpy(&f, &c[0], 16);
    return f;
}

// ---------------- prep: W1 [A][LAT][HID] fp32 -> frag-ordered bf16 ----------
// frag entry e = (nt*2+kk)*64 + lane holds 8 bf16:
//   element j = W1[a][ kk*32 + (lane>>4)*8 + j ][ nt*16 + (lane&15) ]
__global__ __launch_bounds__(256, 2) void prep_w1(
    const float* __restrict__ W1, short* __restrict__ w1f)
{
    __shared__ float lds[LAT * HID];   // 32 KB fp32
    const int a   = blockIdx.x;
    const int tid = threadIdx.x;

    const float4* src = reinterpret_cast<const float4*>(W1 + (size_t)a * (LAT * HID));
    float4* ldsv = reinterpret_cast<float4*>(lds);
    #pragma unroll
    for (int i = 0; i < (LAT * HID / 4) / 256; ++i)
        ldsv[i * 256 + tid] = src[i * 256 + tid];
    __syncthreads();

    bf16x8* dst = reinterpret_cast<bf16x8*>(w1f + (size_t)a * (LAT * HID));
    #pragma unroll
    for (int i = 0; i < 4; ++i) {
        const int e    = i * 256 + tid;
        const int nt   = e >> 7;
        const int kk   = (e >> 6) & 1;
        const int lane = e & 63;
        const int n  = nt * 16 + (lane & 15);
        const int k0 = kk * 32 + (lane >> 4) * 8;
        bf16x8 f;
        #pragma unroll
        for (int j = 0; j < 8; ++j)
            f[j] = f2bf(lds[(k0 + j) * HID + n]);
        dst[e] = f;
    }
}

// issue the 8 dwordx4 x-loads for chunk (tile T, half H) into xr[0..7]
#define ISSUE_LOADS(T, H)                                                       \
    do {                                                                        \
        const int a_  = (T) % NA;                                               \
        const int bt_ = (T) / NA;                                               \
        const int rb_ = bt_ * MB + w * 64 + (H) * 32;                           \
        _Pragma("unroll")                                                       \
        for (int mt = 0; mt < 2; ++mt) {                                        \
            const float* xrow_ = x + (size_t)(rb_ + mt * 16 + llo) * (NA * LAT) \
                                   + (size_t)a_ * LAT;                          \
            _Pragma("unroll")                                                   \
            for (int kk = 0; kk < 2; ++kk) {                                    \
                const float4* p_ = reinterpret_cast<const float4*>(             \
                    xrow_ + kk * 32 + lhi * 8);                                 \
                xr[mt * 4 + kk * 2 + 0] = p_[0];                                \
                xr[mt * 4 + kk * 2 + 1] = p_[1];                                \
            }                                                                   \
        }                                                                       \
    } while (0)

// ---------------- main: persistent, chunk-pipelined, no LDS -----------------
// 512 blocks x 4 independent waves. Each wave streams 32-row chunks:
// pack previous chunk's raw x -> afrag (frees regs), issue next chunk's
// 8 dwordx4 (HBM latency hides under current chunk's MFMA+epilogue), compute.
__global__ __launch_bounds__(256, 2) void attr_decoder_main(
    const float* __restrict__ x,
    const short* __restrict__ w1f,
    const float* __restrict__ b1,
    const float* __restrict__ W2,
    const float* __restrict__ b2,
    float* __restrict__ out)
{
    const int tid  = threadIdx.x;
    const int w    = tid >> 6;
    const int lane = tid & 63;
    const int llo  = lane & 15;
    const int lhi  = lane >> 4;

    float4 xr[8];   // raw x of the chunk currently in flight

    int t = blockIdx.x;
    if (t >= NT) return;
    ISSUE_LOADS(t, 0);

    while (true) {
        #pragma unroll 1
        for (int h = 0; h < 2; ++h) {
            // xr holds chunk (t, h): convert to MFMA A-fragments
            bf16x8 af[2][2];
            #pragma unroll
            for (int mt = 0; mt < 2; ++mt)
                #pragma unroll
                for (int kk = 0; kk < 2; ++kk)
                    af[mt][kk] = pack8(xr[mt * 4 + kk * 2], xr[mt * 4 + kk * 2 + 1]);

            // issue next chunk's loads (overlap with compute below)
            const int tn = (h == 0) ? t : t + GRID;
            if (h == 0) {
                ISSUE_LOADS(tn, 1);
            } else if (tn < NT) {
                ISSUE_LOADS(tn, 0);
            }

            // ---- compute chunk (t, h) ----
            const int a  = t % NA;
            const int bt = t / NA;
            const bf16x8* wf  = reinterpret_cast<const bf16x8*>(w1f + (size_t)a * (LAT * HID));
            const float*  b1a = b1 + a * HID;
            const float*  w2a = W2 + a * HID;
            float p2[2][4] = {};
            #pragma unroll 4
            for (int nt = 0; nt < 8; ++nt) {
                const bf16x8 bf0 = wf[(nt * 2 + 0) * 64 + lane];   // L1-resident
                const bf16x8 bf1 = wf[(nt * 2 + 1) * 64 + lane];
                const int n = nt * 16 + llo;
                const float b1v = b1a[n];
                const float w2v = w2a[n];
                const f32x4 cin = {b1v, b1v, b1v, b1v};
                #pragma unroll
                for (int mt = 0; mt < 2; ++mt) {
                    f32x4 acc = cin;
                    acc = __builtin_amdgcn_mfma_f32_16x16x32_bf16(af[mt][0], bf0, acc, 0, 0, 0);
                    acc = __builtin_amdgcn_mfma_f32_16x16x32_bf16(af[mt][1], bf1, acc, 0, 0, 0);
                    #pragma unroll
                    for (int r = 0; r < 4; ++r)
                        p2[mt][r] = fmaf(fmaxf(acc[r], 0.f), w2v, p2[mt][r]);
                }
            }

            // ---- epilogue: reduce over n-lanes, sigmoid, store ----
            const float ob = b2[a];
            const int rowbase = bt * MB + w * 64 + h * 32;
            #pragma unroll
            for (int mt = 0; mt < 2; ++mt) {
                #pragma unroll
                for (int r = 0; r < 4; ++r) {
                    float s = p2[mt][r];
                    s += __shfl_xor(s, 1);
                    s += __shfl_xor(s, 2);
                    s += __shfl_xor(s, 4);
                    s += __shfl_xor(s, 8);
                    s = 1.0f / (1.0f + __expf(-(s + ob)));
                    if (llo == 0) {
                        const int row = rowbase + mt * 16 + lhi * 4 + r;
                        out[(size_t)row * NA + a] = s;
                    }
                }
            }
        }
        t += GRID;
        if (t >= NT) break;
    }
}

extern "C" void kernel_launch(void* const* d_in, const int* in_sizes, int n_in,
                              void* d_out, int out_size, void* d_ws, size_t ws_size,
                              hipStream_t stream) {
    const float* x  = (const float*)d_in[0];
    const float* W1 = (const float*)d_in[1];
    const float* b1 = (const float*)d_in[2];
    const float* W2 = (const float*)d_in[3];
    const float* b2 = (const float*)d_in[4];
    float* out = (float*)d_out;
    short* w1f = (short*)d_ws;          // 312*8192 bf16 = 5.1 MB

    hipLaunchKernelGGL(prep_w1, dim3(NA), dim3(256), 0, stream, W1, w1f);
    hipLaunchKernelGGL(attr_decoder_main, dim3(GRID), dim3(256), 0, stream,
                       x, w1f, b1, W2, b2, out);
}

// Round 8
// 249.342 us; speedup vs baseline: 1.0752x; 1.0752x over previous
//
#include <hip/hip_runtime.h>
#include <hip/hip_bf16.h>

#define NA   312      // attributes
#define LAT  64       // latent per attribute (K)
#define HID  128      // hidden per attribute (N)
#define NB   8192     // batch
#define AG   8        // attributes per block
#define NAG  (NA / AG)    // 39 attribute groups
#define RB   64       // rows per block
#define NBT  (NB / RB)    // 128 batch tiles

typedef __attribute__((ext_vector_type(8))) short bf16x8;
typedef __attribute__((ext_vector_type(4))) float f32x4;

// fp32 -> bf16 RNE scalar (prep kernel only)
__device__ inline short f2bf(float f) {
    unsigned u = __builtin_bit_cast(unsigned, f);
    u += 0x7FFFu + ((u >> 16) & 1u);
    return (short)(u >> 16);
}

// 8x fp32 -> bf16x8; __float22bfloat162_rn lowers to v_cvt_pk_bf16_f32.
__device__ inline bf16x8 pack8(float4 v0, float4 v1) {
    __hip_bfloat162 c[4] = {
        __float22bfloat162_rn(float2{v0.x, v0.y}),
        __float22bfloat162_rn(float2{v0.z, v0.w}),
        __float22bfloat162_rn(float2{v1.x, v1.y}),
        __float22bfloat162_rn(float2{v1.z, v1.w})};
    bf16x8 f;
    __builtin_memcpy(&f, &c[0], 16);
    return f;
}

// ---------------- prep: W1 [A][LAT][HID] fp32 -> frag-ordered bf16 ----------
// frag entry e = (nt*2+kk)*64 + lane holds 8 bf16:
//   element j = W1[a][ kk*32 + (lane>>4)*8 + j ][ nt*16 + (lane&15) ]
__global__ __launch_bounds__(256, 2) void prep_w1(
    const float* __restrict__ W1, short* __restrict__ w1f)
{
    __shared__ float lds[LAT * HID];   // 32 KB fp32
    const int a   = blockIdx.x;
    const int tid = threadIdx.x;

    const float4* src = reinterpret_cast<const float4*>(W1 + (size_t)a * (LAT * HID));
    float4* ldsv = reinterpret_cast<float4*>(lds);
    #pragma unroll
    for (int i = 0; i < (LAT * HID / 4) / 256; ++i)
        ldsv[i * 256 + tid] = src[i * 256 + tid];
    __syncthreads();

    bf16x8* dst = reinterpret_cast<bf16x8*>(w1f + (size_t)a * (LAT * HID));
    #pragma unroll
    for (int i = 0; i < 4; ++i) {
        const int e    = i * 256 + tid;
        const int nt   = e >> 7;
        const int kk   = (e >> 6) & 1;
        const int lane = e & 63;
        const int n  = nt * 16 + (lane & 15);
        const int k0 = kk * 32 + (lane >> 4) * 8;
        bf16x8 f;
        #pragma unroll
        for (int j = 0; j < 8; ++j)
            f[j] = f2bf(lds[(k0 + j) * HID + n]);
        dst[e] = f;
    }
}

// ---------------- main: attribute-grouped, LDS-staged x ---------------------
// One block: 8 attrs x 64 rows. Stage reads 2 KB CONTIGUOUS per row (DRAM
// page locality), converts to bf16, stores to XOR-swizzled LDS. Each wave
// computes its 16 rows x 8 attrs: A-frags from LDS (conflict-free), B-frags
// from frag-ordered w1f (L2-resident). Layer 2 + sigmoid fused, in-wave.
__global__ __launch_bounds__(256, 2) void attr_decoder_main(
    const float* __restrict__ x,
    const short* __restrict__ w1f,
    const float* __restrict__ b1,
    const float* __restrict__ W2,
    const float* __restrict__ b2,
    float* __restrict__ out)
{
    __shared__ short xs[RB * AG * LAT];   // 64 rows x 512 bf16 = 64 KB

    const int tid  = threadIdx.x;
    const int ag   = blockIdx.x >> 7;     // /NBT: co-resident blocks span rows
    const int bt   = blockIdx.x & (NBT - 1);
    const int row0 = bt * RB;

    // ---- stage: row-major bf16, slot-swizzled (slot = lt ^ (r&7)) ----
    {
        const int lt = tid & 63;          // 64 slots of 16 B per 1 KB row
        const int rw = tid >> 6;
        bf16x8* xs16 = reinterpret_cast<bf16x8*>(xs);
        #pragma unroll
        for (int i = 0; i < 16; ++i) {
            const int r = i * 4 + rw;
            const float4* p = reinterpret_cast<const float4*>(
                x + (size_t)(row0 + r) * (NA * LAT) + ag * (AG * LAT)) + lt * 2;
            xs16[r * 64 + (lt ^ (r & 7))] = pack8(p[0], p[1]);   // 2 KB span/row
        }
    }
    __syncthreads();

    const int w    = tid >> 6;          // wave id: rows w*16 .. w*16+15 (local)
    const int lane = tid & 63;
    const int llo  = lane & 15;
    const int lhi  = lane >> 4;
    const int arow = w * 16 + llo;      // this lane's A-row (local)
    const bf16x8* xsv = reinterpret_cast<const bf16x8*>(xs);

    #pragma unroll 1
    for (int al = 0; al < AG; ++al) {
        const int a = ag * AG + al;
        // A-frags from LDS: logical slot al*8 + kk*4 + lhi, phys ^= (arow&7)
        const bf16x8 af0 = xsv[arow * 64 + ((al * 8 +     lhi) ^ (arow & 7))];
        const bf16x8 af1 = xsv[arow * 64 + ((al * 8 + 4 + lhi) ^ (arow & 7))];

        const bf16x8* wf  = reinterpret_cast<const bf16x8*>(w1f + (size_t)a * (LAT * HID));
        const float*  b1a = b1 + a * HID;
        const float*  w2a = W2 + a * HID;
        float p2[4] = {};
        #pragma unroll
        for (int nt = 0; nt < 8; ++nt) {
            const bf16x8 bf0 = wf[(nt * 2 + 0) * 64 + lane];
            const bf16x8 bf1 = wf[(nt * 2 + 1) * 64 + lane];
            const int n = nt * 16 + llo;
            const float b1v = b1a[n];
            const float w2v = w2a[n];
            f32x4 acc = {b1v, b1v, b1v, b1v};
            acc = __builtin_amdgcn_mfma_f32_16x16x32_bf16(af0, bf0, acc, 0, 0, 0);
            acc = __builtin_amdgcn_mfma_f32_16x16x32_bf16(af1, bf1, acc, 0, 0, 0);
            #pragma unroll
            for (int r = 0; r < 4; ++r)
                p2[r] = fmaf(fmaxf(acc[r], 0.f), w2v, p2[r]);
        }

        // reduce over n-lanes, sigmoid, store
        const float ob = b2[a];
        #pragma unroll
        for (int r = 0; r < 4; ++r) {
            float s = p2[r];
            s += __shfl_xor(s, 1);
            s += __shfl_xor(s, 2);
            s += __shfl_xor(s, 4);
            s += __shfl_xor(s, 8);
            s = 1.0f / (1.0f + __expf(-(s + ob)));
            if (llo == 0) {
                const int row = row0 + w * 16 + lhi * 4 + r;
                out[(size_t)row * NA + a] = s;
            }
        }
    }
}

extern "C" void kernel_launch(void* const* d_in, const int* in_sizes, int n_in,
                              void* d_out, int out_size, void* d_ws, size_t ws_size,
                              hipStream_t stream) {
    const float* x  = (const float*)d_in[0];
    const float* W1 = (const float*)d_in[1];
    const float* b1 = (const float*)d_in[2];
    const float* W2 = (const float*)d_in[3];
    const float* b2 = (const float*)d_in[4];
    float* out = (float*)d_out;
    short* w1f = (short*)d_ws;          // 312*8192 bf16 = 5.1 MB

    hipLaunchKernelGGL(prep_w1, dim3(NA), dim3(256), 0, stream, W1, w1f);
    hipLaunchKernelGGL(attr_decoder_main, dim3(NAG * NBT), dim3(256), 0, stream,
                       x, w1f, b1, W2, b2, out);
}